// Round 3
// baseline (319.490 us; speedup 1.0000x reference)
//
#include <hip/hip_runtime.h>
#include <hip/hip_bf16.h>

// Butterfly structure (BASE=3, FACTOR=0, n=27):
//   mask[s,t] != 0  iff  floor(s1/3)==floor(t1/3) && floor(s2/3)==floor(t2/3)
//   where s = 27*s1 + s2.  => 81 groups (G1,G2) in [0,9)x[0,9); each group
//   couples 9 s-indices with 9 t-indices:
//     s = 81*G1 + 27*i + 3*G2 + j,  i,j in [0,3)   (same formula for t)
//   attn stored packed: attn[g*81 + ls*9 + lt], g = 9*G1+G2, ls=3i+j of s,
//   lt=3i+j of t.
//
// Dtype evidence: round 1 (inputs as bf16) -> NaN  => inputs are fp32.
//                 round 2 (out as bf16)    -> 0.749 error with the exact
//                 signature of a half-written fp32 buffer => output is fp32.

__device__ __forceinline__ float gelu_f(float v) {
    // tanh-form gelu: v * sigmoid(2*0.7978845608*(v + 0.044715 v^3))
    // |err| < ~7e-4 absolute; threshold is 1.44e-2.
    float u2 = v * v;
    float z = -1.5957691216f * v * fmaf(0.044715f, u2, 1.0f);
    float e = __expf(z);
    return v / (1.0f + e);
}

// ---------------- Kernel 1: block-sparse attn = (w1^T . w2^T) .* mask ------
// grid 81 (one per group), 512 threads. Output: attn[81*81] fp32 in ws.
__global__ __launch_bounds__(512) void bfly_attn_kernel(
        const float* __restrict__ w1,   // [2916, 729]
        const float* __restrict__ w2,   // [729, 2916]
        float* __restrict__ attn)       // [81*81]
{
    const int g  = blockIdx.x;
    const int G1 = g / 9, G2 = g % 9;
    const int tid = threadIdx.x;

    int idx[9];
    #pragma unroll
    for (int i = 0; i < 3; ++i)
        #pragma unroll
        for (int j = 0; j < 3; ++j)
            idx[3*i + j] = 81*G1 + 27*i + 3*G2 + j;

    float acc[81];
    #pragma unroll
    for (int k = 0; k < 81; ++k) acc[k] = 0.0f;

    for (int d = tid; d < 2916; d += 512) {
        float a[9], b[9];
        #pragma unroll
        for (int k = 0; k < 9; ++k) {
            a[k] = w1[d * 729 + idx[k]];      // column of w1 (strided, L2/L3-hot)
            b[k] = w2[idx[k] * 2916 + d];     // row of w2 (coalesced)
        }
        #pragma unroll
        for (int ls = 0; ls < 9; ++ls)
            #pragma unroll
            for (int lt = 0; lt < 9; ++lt)
                acc[ls*9 + lt] = fmaf(a[ls], b[lt], acc[ls*9 + lt]);
    }

    __shared__ float red[8][81];
    const int lane = tid & 63, wave = tid >> 6;
    #pragma unroll
    for (int k = 0; k < 81; ++k) {
        float v = acc[k];
        #pragma unroll
        for (int off = 32; off > 0; off >>= 1)
            v += __shfl_down(v, off, 64);
        if (lane == 0) red[wave][k] = v;
    }
    __syncthreads();
    if (tid < 81) {
        float s = 0.0f;
        #pragma unroll
        for (int w = 0; w < 8; ++w) s += red[w][tid];
        attn[g * 81 + tid] = s;
    }
}

// ---------------- Kernel 2: out = gelu(x @ attn_blocksparse + b2) ----------
#define ROWS 16

__global__ __launch_bounds__(256) void bfly_mlp_kernel(
        const float* __restrict__ xg,    // [49152, 729] fp32
        const float* __restrict__ attn,  // [81*81] fp32 (ws)
        const float* __restrict__ b2g,   // [729] fp32
        float* __restrict__ outg)        // [49152, 729] fp32
{
    __shared__ float xs[ROWS * 729];     // 46656 B -> 3 blocks/CU

    const int tid = threadIdx.x;
    const long long rowbase = (long long)blockIdx.x * ROWS;

    // Stage x tile: ROWS*729*4/16 = 2916 uint4 loads, fully coalesced.
    // Base byte offset = blockIdx * ROWS*729*4 (16B-aligned).
    {
        const uint4* src = (const uint4*)(xg + rowbase * 729);
        uint4* dst = (uint4*)xs;
        for (int i = tid; i < (ROWS * 729) / 4; i += 256) dst[i] = src[i];
    }
    __syncthreads();

    if (tid < 243) {
        const int t1 = tid / 9;           // 0..26
        const int G2 = tid % 9;           // 0..8
        const int G1 = t1 / 3;
        const int li = t1 % 3;            // local i of the t-triple
        const int tb = 27 * t1 + 3 * G2;  // == 3*tid: contiguous stores
        const int sb = 81 * G1 + 3 * G2;  // s gather base
        const int g  = 9 * G1 + G2;

        // Hoist the 27 attn weights (global, L2-resident after first blocks).
        float a[9][3];
        #pragma unroll
        for (int ls = 0; ls < 9; ++ls)
            #pragma unroll
            for (int j = 0; j < 3; ++j)
                a[ls][j] = attn[g * 81 + ls * 9 + 3 * li + j];

        float bias[3];
        #pragma unroll
        for (int j = 0; j < 3; ++j) bias[j] = b2g[tb + j];

        for (int r = 0; r < ROWS; ++r) {
            const int xb = r * 729 + sb;
            float xv[9];
            #pragma unroll
            for (int i2 = 0; i2 < 3; ++i2)
                #pragma unroll
                for (int j2 = 0; j2 < 3; ++j2)
                    xv[3*i2 + j2] = xs[xb + 27*i2 + j2];

            float acc0 = bias[0], acc1 = bias[1], acc2 = bias[2];
            #pragma unroll
            for (int ls = 0; ls < 9; ++ls) {
                acc0 = fmaf(xv[ls], a[ls][0], acc0);
                acc1 = fmaf(xv[ls], a[ls][1], acc1);
                acc2 = fmaf(xv[ls], a[ls][2], acc2);
            }

            const long long ob = (rowbase + r) * 729 + tb;
            outg[ob + 0] = gelu_f(acc0);
            outg[ob + 1] = gelu_f(acc1);
            outg[ob + 2] = gelu_f(acc2);
        }
    }
}

extern "C" void kernel_launch(void* const* d_in, const int* in_sizes, int n_in,
                              void* d_out, int out_size, void* d_ws, size_t ws_size,
                              hipStream_t stream) {
    const float* x  = (const float*)d_in[0];  // [64,768,729]
    const float* w1 = (const float*)d_in[1];  // [2916,729]
    const float* w2 = (const float*)d_in[2];  // [729,2916]
    const float* b2 = (const float*)d_in[3];  // [729]
    // d_in[4] = sparse_mask: structure is static (butterfly), never read.

    float* attn = (float*)d_ws;  // 26244 B scratch

    bfly_attn_kernel<<<81, 512, 0, stream>>>(w1, w2, attn);

    const int n_rows = 64 * 768;             // 49152
    bfly_mlp_kernel<<<n_rows / ROWS, 256, 0, stream>>>(
        x, attn, b2, (float*)d_out);
}

// Round 4
// 281.498 us; speedup vs baseline: 1.1350x; 1.1350x over previous
//
#include <hip/hip_runtime.h>
#include <hip/hip_bf16.h>

// Butterfly structure (BASE=3, FACTOR=0, n=27):
//   mask[s,t] != 0  iff  floor(s1/3)==floor(t1/3) && floor(s2/3)==floor(t2/3),
//   s = 27*s1 + s2.  81 groups g=(G1,G2); group members: 81*G1 + 27*i + 3*G2 + j.
//   Key coalescing fact: all 9 groups with the same G1 draw from the single
//   contiguous column band [81*G1, 81*G1+81) of w1 — so w1 can be read in
//   contiguous 324 B row-segments with zero waste.
//   attn packed: attn[g*81 + ls*9 + lt], g = 9*G1+G2, ls/lt = 3i+j.
//
// Dtypes (verified round 3): inputs fp32, output fp32.

__device__ __forceinline__ float gelu_f(float v) {
    // tanh-form gelu; |err| < ~7e-4, threshold 1.44e-2 (round-3 absmax 3.9e-3).
    float u2 = v * v;
    float z = -1.5957691216f * v * fmaf(0.044715f, u2, 1.0f);
    float e = __expf(z);
    return v * __builtin_amdgcn_rcpf(1.0f + e);
}

// ---------------- Kernel 0: zero attn scratch (ws is poisoned 0xAA) --------
__global__ void attn_zero_kernel(float* __restrict__ attn) {
    int i = blockIdx.x * 256 + threadIdx.x;
    if (i < 81 * 81) attn[i] = 0.0f;
}

// ---------------- Kernel 1: block-sparse attn = (w1^T . w2^T) .* mask ------
// grid = 9 G1-bands x 27 d-chunks = 243 blocks, 256 threads.
// Per block: stage w1[81x CH band] + w2[81 rows x CH] in LDS (coalesced,
// every byte used -> total global traffic exactly w1+w2 = 17 MB), compute
// 729 masked entries, atomicAdd partials.
#define CH 108   // 27 chunks * 108 = 2916

__global__ __launch_bounds__(256) void bfly_attn_kernel(
        const float* __restrict__ w1,   // [2916, 729]
        const float* __restrict__ w2,   // [729, 2916]
        float* __restrict__ attn)       // [81*81], pre-zeroed
{
    const int G1    = blockIdx.x % 9;
    const int d0    = (blockIdx.x / 9) * CH;
    const int tid   = threadIdx.x;

    __shared__ float ws1[CH * 81];      // [dl][c]   34992 B
    __shared__ float ws2[81 * CH];      // [tl][dl]  34992 B

    // w1 band tile: rows d0..d0+CH, cols 81*G1..+81. Consecutive threads ->
    // consecutive cols within a 324 B segment: coalesced.
    for (int i = tid; i < CH * 81; i += 256) {
        int dl = i / 81, c = i % 81;
        ws1[i] = w1[(d0 + dl) * 729 + 81 * G1 + c];
    }
    // w2 tile: 81 rows x CH cols of d. Consecutive threads -> consecutive d:
    // coalesced 432 B segments.
    for (int i = tid; i < 81 * CH; i += 256) {
        int tl = i / CH, dl = i % CH;
        ws2[i] = w2[(81 * G1 + tl) * 2916 + d0 + dl];
    }
    __syncthreads();

    if (tid < 243) {
        // entries e = 3*tid + j, e = G2*81 + ls*9 + lt; the 3 share (G2, ls).
        const int G2  = tid / 27;
        const int ls  = (tid % 27) / 3;
        const int lt0 = (tid % 3) * 3;
        const int s_l = 27 * (ls / 3) + 3 * G2 + (ls % 3);
        int t_l[3];
        #pragma unroll
        for (int j = 0; j < 3; ++j) {
            int lt = lt0 + j;
            t_l[j] = 27 * (lt / 3) + 3 * G2 + (lt % 3);
        }

        float a0 = 0.f, a1 = 0.f, a2 = 0.f;
        for (int dl = 0; dl < CH; ++dl) {
            float av = ws1[dl * 81 + s_l];       // shared by 3 outputs
            a0 = fmaf(av, ws2[t_l[0] * CH + dl], a0);
            a1 = fmaf(av, ws2[t_l[1] * CH + dl], a1);
            a2 = fmaf(av, ws2[t_l[2] * CH + dl], a2);
        }

        const int g = 9 * G1 + G2;
        float* dst = &attn[g * 81 + ls * 9 + lt0];
        atomicAdd(dst + 0, a0);
        atomicAdd(dst + 1, a1);
        atomicAdd(dst + 2, a2);
    }
}

// ---------------- Kernel 2: out = gelu(x @ attn_blocksparse + b2) ----------
// ROWS=8: LDS 23328 B -> 6 blocks/CU = 24/32 waves (was 16 -> 3 blocks, 30%).
#define ROWS 8

__global__ __launch_bounds__(256) void bfly_mlp_kernel(
        const float* __restrict__ xg,    // [49152, 729] fp32
        const float* __restrict__ attn,  // [81*81] fp32 (ws)
        const float* __restrict__ b2g,   // [729] fp32
        float* __restrict__ outg)        // [49152, 729] fp32
{
    __shared__ float xs[ROWS * 729];     // 23328 B

    const int tid = threadIdx.x;
    const long long rowbase = (long long)blockIdx.x * ROWS;

    // Hoist weight/bias loads ABOVE the staging barrier so their global
    // latency overlaps the x-tile staging.
    float a[9][3], bias[3];
    int tb = 0, sb = 0;
    const bool active = (tid < 243);
    if (active) {
        const int t1 = tid / 9;           // 0..26
        const int G2 = tid % 9;           // 0..8
        const int G1 = t1 / 3;
        const int li = t1 % 3;
        tb = 27 * t1 + 3 * G2;            // == 3*tid: contiguous stores
        sb = 81 * G1 + 3 * G2;
        const int g  = 9 * G1 + G2;
        #pragma unroll
        for (int ls = 0; ls < 9; ++ls)
            #pragma unroll
            for (int j = 0; j < 3; ++j)
                a[ls][j] = attn[g * 81 + ls * 9 + 3 * li + j];
        #pragma unroll
        for (int j = 0; j < 3; ++j) bias[j] = b2g[tb + j];
    }

    // Stage x tile: ROWS*729/4 = 1458 uint4 loads, fully coalesced
    // (base byte offset blockIdx*ROWS*2916 is 16B-aligned).
    {
        const uint4* src = (const uint4*)(xg + rowbase * 729);
        uint4* dst = (uint4*)xs;
        for (int i = tid; i < (ROWS * 729) / 4; i += 256) dst[i] = src[i];
    }
    __syncthreads();

    if (active) {
        #pragma unroll 2
        for (int r = 0; r < ROWS; ++r) {
            const int xb = r * 729 + sb;
            float xv[9];
            #pragma unroll
            for (int i2 = 0; i2 < 3; ++i2)
                #pragma unroll
                for (int j2 = 0; j2 < 3; ++j2)
                    xv[3*i2 + j2] = xs[xb + 27*i2 + j2];

            float acc0 = bias[0], acc1 = bias[1], acc2 = bias[2];
            #pragma unroll
            for (int ls = 0; ls < 9; ++ls) {
                acc0 = fmaf(xv[ls], a[ls][0], acc0);
                acc1 = fmaf(xv[ls], a[ls][1], acc1);
                acc2 = fmaf(xv[ls], a[ls][2], acc2);
            }

            const long long ob = (rowbase + r) * 729 + tb;
            outg[ob + 0] = gelu_f(acc0);
            outg[ob + 1] = gelu_f(acc1);
            outg[ob + 2] = gelu_f(acc2);
        }
    }
}

extern "C" void kernel_launch(void* const* d_in, const int* in_sizes, int n_in,
                              void* d_out, int out_size, void* d_ws, size_t ws_size,
                              hipStream_t stream) {
    const float* x  = (const float*)d_in[0];  // [64,768,729]
    const float* w1 = (const float*)d_in[1];  // [2916,729]
    const float* w2 = (const float*)d_in[2];  // [729,2916]
    const float* b2 = (const float*)d_in[3];  // [729]
    // d_in[4] = sparse_mask: static butterfly structure, never read.

    float* attn = (float*)d_ws;  // 26244 B scratch

    attn_zero_kernel<<<26, 256, 0, stream>>>(attn);
    bfly_attn_kernel<<<9 * 27, 256, 0, stream>>>(w1, w2, attn);

    const int n_rows = 64 * 768;             // 49152
    bfly_mlp_kernel<<<n_rows / ROWS, 256, 0, stream>>>(
        x, attn, b2, (float*)d_out);
}